// Round 4
// baseline (2016.767 us; speedup 1.0000x reference)
//
#include <hip/hip_runtime.h>
#include <hip/hip_bf16.h>
#include <math.h>

// ---------------------------------------------------------------------------
// AttentionEncoderModel on MI355X — round 4: unchunked convs, 128x128/8x8
// split-K GEMM, vectorized glue. Attention kernel unchanged from round 3.
// ---------------------------------------------------------------------------

#define DMODEL 256
#define SEQ    512
#define NHEAD  8
#define DHEAD  32

// ---------------- conv1: 3->16, in 96x120 -> out 48x60 ----------------------
// operates on a window of images; in/out pre-offset by caller
__global__ __launch_bounds__(256) void conv1_kernel(
    const float* __restrict__ in, const float* __restrict__ w,
    const float* __restrict__ bias, float* __restrict__ out) {
  __shared__ float wsm[768];  // 16*3*4*4
  int t = threadIdx.x;
  for (int i = t; i < 768; i += 256) wsm[i] = w[i];
  __syncthreads();
  int idx = blockIdx.x * 256 + t;
  int ox = idx % 60;
  int oy = (idx / 60) % 48;
  int n  = idx / (60 * 48);
  int iy0 = oy * 2 - 1, ix0 = ox * 2 - 1;
  float win[3][16];
  #pragma unroll
  for (int ic = 0; ic < 3; ic++) {
    #pragma unroll
    for (int ky = 0; ky < 4; ky++) {
      int iy = iy0 + ky;
      #pragma unroll
      for (int kx = 0; kx < 4; kx++) {
        int ix = ix0 + kx;
        bool ok = (iy >= 0) && (iy < 96) && (ix >= 0) && (ix < 120);
        win[ic][ky * 4 + kx] = ok ? in[((n * 3 + ic) * 96 + iy) * 120 + ix] : 0.f;
      }
    }
  }
  #pragma unroll
  for (int oc = 0; oc < 16; oc++) {
    float acc = bias[oc];
    const float* wp = &wsm[oc * 48];
    #pragma unroll
    for (int ic = 0; ic < 3; ic++)
      #pragma unroll
      for (int k = 0; k < 16; k++)
        acc = fmaf(win[ic][k], wp[ic * 16 + k], acc);
    out[((n * 16 + oc) * 48 + oy) * 60 + ox] = fmaxf(acc, 0.f);
  }
}

// ---------------- conv 16->16 (conv2 and conv3) -----------------------------
template <int IH, int IW, int OH, int OW>
__global__ __launch_bounds__(256) void conv16_kernel(
    const float* __restrict__ in, const float* __restrict__ w,
    const float* __restrict__ bias, float* __restrict__ out) {
  __shared__ float wsm[4096];  // 16*16*4*4
  int t = threadIdx.x;
  for (int i = t; i < 4096; i += 256) wsm[i] = w[i];
  __syncthreads();
  int idx = blockIdx.x * 256 + t;
  int ox = idx % OW;
  int oy = (idx / OW) % OH;
  int n  = idx / (OW * OH);
  int iy0 = oy * 2 - 1, ix0 = ox * 2 - 1;
  float acc[16];
  #pragma unroll
  for (int oc = 0; oc < 16; oc++) acc[oc] = bias[oc];
  for (int ic = 0; ic < 16; ic++) {
    float win[16];
    #pragma unroll
    for (int ky = 0; ky < 4; ky++) {
      int iy = iy0 + ky;
      #pragma unroll
      for (int kx = 0; kx < 4; kx++) {
        int ix = ix0 + kx;
        bool ok = (iy >= 0) && (iy < IH) && (ix >= 0) && (ix < IW);
        win[ky * 4 + kx] = ok ? in[((n * 16 + ic) * IH + iy) * IW + ix] : 0.f;
      }
    }
    #pragma unroll
    for (int oc = 0; oc < 16; oc++) {
      const float* wp = &wsm[(oc * 16 + ic) * 16];
      float a = acc[oc];
      #pragma unroll
      for (int k = 0; k < 16; k++) a = fmaf(win[k], wp[k], a);
      acc[oc] = a;
    }
  }
  #pragma unroll
  for (int oc = 0; oc < 16; oc++)
    out[((n * 16 + oc) * OH + oy) * OW + ox] = fmaxf(acc[oc], 0.f);
}

// ---------------- 128x128 split-K atomic GEMM, 8x8 microtile ----------------
// C += A[M,K] @ B[K,N] over k-range [z*klen, (z+1)*klen). C pre-initialized.
// Microtile: rows {ty*4..+3, 64+ty*4..+3} x cols {tx*4..+3, 64+tx*4..+3}.
__global__ __launch_bounds__(256, 2) void gemm3_kernel(
    const float* __restrict__ A, const float* __restrict__ B,
    float* __restrict__ C, int M, int N, int K, int klen) {
  __shared__ float As[2][16][132];
  __shared__ float Bs[2][16][128];
  int t = threadIdx.x;
  int m0 = blockIdx.y * 128, n0 = blockIdx.x * 128;
  int kb = blockIdx.z * klen;
  int arow = t >> 2;            // 0..63
  int acol = (t & 3) << 2;      // 0,4,8,12
  int brow = t >> 4;            // 0..15
  int bcol = (t & 15) << 2;     // 0..60
  int ty = t >> 4, tx = t & 15;
  float4 ra0, ra1, rb0, rb1;
  float acc[8][8] = {};

  ra0 = *(const float4*)&A[(size_t)(m0 + arow) * K + kb + acol];
  ra1 = *(const float4*)&A[(size_t)(m0 + 64 + arow) * K + kb + acol];
  rb0 = *(const float4*)&B[(size_t)(kb + brow) * N + n0 + bcol];
  rb1 = *(const float4*)&B[(size_t)(kb + brow) * N + n0 + 64 + bcol];
  As[0][acol + 0][arow] = ra0.x; As[0][acol + 1][arow] = ra0.y;
  As[0][acol + 2][arow] = ra0.z; As[0][acol + 3][arow] = ra0.w;
  As[0][acol + 0][64 + arow] = ra1.x; As[0][acol + 1][64 + arow] = ra1.y;
  As[0][acol + 2][64 + arow] = ra1.z; As[0][acol + 3][64 + arow] = ra1.w;
  *(float4*)&Bs[0][brow][bcol]      = rb0;
  *(float4*)&Bs[0][brow][64 + bcol] = rb1;
  __syncthreads();

  int nk = klen >> 4;
  for (int itk = 0; itk < nk; ++itk) {
    int buf = itk & 1;
    if (itk + 1 < nk) {
      int k0 = kb + ((itk + 1) << 4);
      ra0 = *(const float4*)&A[(size_t)(m0 + arow) * K + k0 + acol];
      ra1 = *(const float4*)&A[(size_t)(m0 + 64 + arow) * K + k0 + acol];
      rb0 = *(const float4*)&B[(size_t)(k0 + brow) * N + n0 + bcol];
      rb1 = *(const float4*)&B[(size_t)(k0 + brow) * N + n0 + 64 + bcol];
    }
    #pragma unroll
    for (int kk = 0; kk < 16; kk++) {
      float4 a0 = *(float4*)&As[buf][kk][ty << 2];
      float4 a1 = *(float4*)&As[buf][kk][64 + (ty << 2)];
      float4 b0 = *(float4*)&Bs[buf][kk][tx << 2];
      float4 b1 = *(float4*)&Bs[buf][kk][64 + (tx << 2)];
      float av[8] = {a0.x, a0.y, a0.z, a0.w, a1.x, a1.y, a1.z, a1.w};
      float bv[8] = {b0.x, b0.y, b0.z, b0.w, b1.x, b1.y, b1.z, b1.w};
      #pragma unroll
      for (int i = 0; i < 8; i++)
        #pragma unroll
        for (int j = 0; j < 8; j++)
          acc[i][j] = fmaf(av[i], bv[j], acc[i][j]);
    }
    if (itk + 1 < nk) {
      int nb = buf ^ 1;
      As[nb][acol + 0][arow] = ra0.x; As[nb][acol + 1][arow] = ra0.y;
      As[nb][acol + 2][arow] = ra0.z; As[nb][acol + 3][arow] = ra0.w;
      As[nb][acol + 0][64 + arow] = ra1.x; As[nb][acol + 1][64 + arow] = ra1.y;
      As[nb][acol + 2][64 + arow] = ra1.z; As[nb][acol + 3][64 + arow] = ra1.w;
      *(float4*)&Bs[nb][brow][bcol]      = rb0;
      *(float4*)&Bs[nb][brow][64 + bcol] = rb1;
    }
    __syncthreads();
  }

  #pragma unroll
  for (int i = 0; i < 8; i++) {
    int m = m0 + ((i < 4) ? (ty * 4 + i) : (64 + ty * 4 + i - 4));
    #pragma unroll
    for (int j = 0; j < 8; j++) {
      int n = n0 + ((j < 4) ? (tx * 4 + j) : (64 + tx * 4 + j - 4));
      atomicAdd(&C[(size_t)m * N + n], acc[i][j]);
    }
  }
}

// ---------------- float4 glue kernels ---------------------------------------
__global__ __launch_bounds__(256) void initpre4_kernel(
    float4* __restrict__ C, const float4* __restrict__ bias,
    const float4* __restrict__ pos) {
  int i = blockIdx.x * 256 + threadIdx.x;   // over 65536
  int n4 = i & 63;
  int m = i >> 6;
  float4 b = bias[n4], p = pos[(m & (SEQ - 1)) * 64 + n4];
  C[i] = make_float4(b.x + p.x, b.y + p.y, b.z + p.z, b.w + p.w);
}

__global__ __launch_bounds__(256) void initbias4_kernel(
    float4* __restrict__ C, const float4* __restrict__ bias, int n4) {
  int i = blockIdx.x * 256 + threadIdx.x;
  C[i] = bias[i % n4];
}

__global__ __launch_bounds__(256) void gelubias4_kernel(
    float4* __restrict__ h, const float4* __restrict__ bias) {
  int i = blockIdx.x * 256 + threadIdx.x;   // over 262144
  float4 v = h[i];
  float4 b = bias[i & 255];
  v.x += b.x; v.y += b.y; v.z += b.z; v.w += b.w;
  const float c = 0.70710678118654752f;
  v.x = 0.5f * v.x * (1.f + erff(v.x * c));
  v.y = 0.5f * v.y * (1.f + erff(v.y * c));
  v.z = 0.5f * v.z * (1.f + erff(v.z * c));
  v.w = 0.5f * v.w * (1.f + erff(v.w * c));
  h[i] = v;
}

__global__ __launch_bounds__(256) void addbias4_kernel(
    float4* __restrict__ C, const float4* __restrict__ bias) {
  int i = blockIdx.x * 256 + threadIdx.x;   // over 65536
  float4 v = C[i], b = bias[i & 63];
  v.x += b.x; v.y += b.y; v.z += b.z; v.w += b.w;
  C[i] = v;
}

// ---------------- LayerNorm: one wave per row of 256 ------------------------
__global__ __launch_bounds__(256) void ln_kernel(
    const float* __restrict__ x, const float* __restrict__ g,
    const float* __restrict__ b, float* __restrict__ out) {
  int lane = threadIdx.x & 63;
  int wid  = threadIdx.x >> 6;
  int row  = blockIdx.x * 4 + wid;
  const float* xr = x + row * DMODEL;
  float v[4];
  #pragma unroll
  for (int i = 0; i < 4; i++) v[i] = xr[lane + 64 * i];
  float s = v[0] + v[1] + v[2] + v[3];
  #pragma unroll
  for (int o = 32; o >= 1; o >>= 1) s += __shfl_xor(s, o);
  float mu = s * (1.f / 256.f);
  float sq = 0.f;
  #pragma unroll
  for (int i = 0; i < 4; i++) { float d = v[i] - mu; sq = fmaf(d, d, sq); }
  #pragma unroll
  for (int o = 32; o >= 1; o >>= 1) sq += __shfl_xor(sq, o);
  float rs = rsqrtf(sq * (1.f / 256.f) + 1e-5f);
  float* orow = out + row * DMODEL;
  #pragma unroll
  for (int i = 0; i < 4; i++) {
    int c = lane + 64 * i;
    orow[c] = (v[i] - mu) * rs * g[c] + b[c];
  }
}

// ---------------- fused flash attention (round 3, unchanged) ----------------
__global__ __launch_bounds__(256) void attn_fused_kernel(
    const float* __restrict__ qkv, float* __restrict__ x) {
  __shared__ float Qs[16][36];
  __shared__ float KVs[64][36];
  __shared__ float Osm[16][16][34];

  int t  = threadIdx.x;
  int it = blockIdx.x & 31;
  int h  = (blockIdx.x >> 5) & 7;
  int b  = blockIdx.x >> 8;
  int i0 = it * 16;
  int r  = t >> 4;
  int tx = t & 15;
  int i  = i0 + r;
  int njt = (it >> 2) + 1;

  if (t < 128) {
    int qrow = t >> 3, qd4 = t & 7;
    *(float4*)&Qs[qrow][qd4 * 4] =
        *(const float4*)&qkv[(b * SEQ + i0 + qrow) * 768 + h * 32 + qd4 * 4];
  }
  __syncthreads();
  float4 qv[8];
  #pragma unroll
  for (int d4 = 0; d4 < 8; d4++) qv[d4] = *(float4*)&Qs[r][d4 * 4];

  float s[32];
  #pragma unroll
  for (int z = 0; z < 32; z++) s[z] = -1e30f;

  int kr = t >> 2, kd4 = t & 3;

  #pragma unroll
  for (int jt = 0; jt < 8; jt++) {
    if (jt < njt) {
      int j0 = jt * 64;
      const float* kb = &qkv[(b * SEQ + j0 + kr) * 768 + DMODEL + h * 32];
      *(float4*)&KVs[kr][kd4 * 4]       = *(const float4*)&kb[kd4 * 4];
      *(float4*)&KVs[kr][(kd4 + 4) * 4] = *(const float4*)&kb[(kd4 + 4) * 4];
      __syncthreads();
      #pragma unroll
      for (int q = 0; q < 4; q++) {
        int jl = q * 16 + tx;
        int j  = j0 + jl;
        float acc = 0.f;
        #pragma unroll
        for (int d4 = 0; d4 < 8; d4++) {
          float4 kv = *(float4*)&KVs[jl][d4 * 4];
          acc = fmaf(qv[d4].x, kv.x, acc);
          acc = fmaf(qv[d4].y, kv.y, acc);
          acc = fmaf(qv[d4].z, kv.z, acc);
          acc = fmaf(qv[d4].w, kv.w, acc);
        }
        s[jt * 4 + q] = (j <= i) ? acc * 0.17677669529663687f : -1e30f;
      }
      __syncthreads();
    }
  }

  float mx = -1e30f;
  #pragma unroll
  for (int z = 0; z < 32; z++) mx = fmaxf(mx, s[z]);
  #pragma unroll
  for (int o = 8; o >= 1; o >>= 1) mx = fmaxf(mx, __shfl_xor(mx, o, 16));
  float sum = 0.f;
  #pragma unroll
  for (int z = 0; z < 32; z++) {
    float e = expf(s[z] - mx);
    s[z] = e;
    sum += e;
  }
  #pragma unroll
  for (int o = 8; o >= 1; o >>= 1) sum += __shfl_xor(sum, o, 16);
  float inv = 1.f / sum;
  #pragma unroll
  for (int z = 0; z < 32; z++) s[z] *= inv;

  float o[32];
  #pragma unroll
  for (int z = 0; z < 32; z++) o[z] = 0.f;

  #pragma unroll
  for (int jt = 0; jt < 8; jt++) {
    if (jt < njt) {
      int j0 = jt * 64;
      const float* vb = &qkv[(b * SEQ + j0 + kr) * 768 + 2 * DMODEL + h * 32];
      *(float4*)&KVs[kr][kd4 * 4]       = *(const float4*)&vb[kd4 * 4];
      *(float4*)&KVs[kr][(kd4 + 4) * 4] = *(const float4*)&vb[(kd4 + 4) * 4];
      __syncthreads();
      #pragma unroll
      for (int q = 0; q < 4; q++) {
        int jl = q * 16 + tx;
        float p = s[jt * 4 + q];
        #pragma unroll
        for (int d4 = 0; d4 < 8; d4++) {
          float4 vv = *(float4*)&KVs[jl][d4 * 4];
          o[d4 * 4 + 0] = fmaf(p, vv.x, o[d4 * 4 + 0]);
          o[d4 * 4 + 1] = fmaf(p, vv.y, o[d4 * 4 + 1]);
          o[d4 * 4 + 2] = fmaf(p, vv.z, o[d4 * 4 + 2]);
          o[d4 * 4 + 3] = fmaf(p, vv.w, o[d4 * 4 + 3]);
        }
      }
      __syncthreads();
    }
  }

  #pragma unroll
  for (int d2 = 0; d2 < 16; d2++)
    *(float2*)&Osm[r][tx][d2 * 2] = make_float2(o[d2 * 2], o[d2 * 2 + 1]);
  __syncthreads();
  float2 acc2 = make_float2(0.f, 0.f);
  #pragma unroll
  for (int tx2 = 0; tx2 < 16; tx2++) {
    float2 v = *(float2*)&Osm[r][tx2][tx * 2];
    acc2.x += v.x;
    acc2.y += v.y;
  }
  int base = (b * SEQ + i) * DMODEL + h * 32 + tx * 2;
  float2 old = *(float2*)&x[base];
  old.x += acc2.x;
  old.y += acc2.y;
  *(float2*)&x[base] = old;
}

// ---------------- global standardization ------------------------------------
__global__ __launch_bounds__(256) void reduce1_kernel(
    const float* __restrict__ enc, double* __restrict__ part) {
  int t = threadIdx.x;
  double s = 0.0, q = 0.0;
  for (int i = blockIdx.x * 256 + t; i < 262144; i += 256 * 256) {
    double v = (double)enc[i];
    s += v; q += v * v;
  }
  #pragma unroll
  for (int o = 32; o >= 1; o >>= 1) { s += __shfl_xor(s, o); q += __shfl_xor(q, o); }
  __shared__ double ls[4], lq[4];
  int lane = t & 63, wid = t >> 6;
  if (lane == 0) { ls[wid] = s; lq[wid] = q; }
  __syncthreads();
  if (t == 0) {
    part[blockIdx.x * 2]     = ls[0] + ls[1] + ls[2] + ls[3];
    part[blockIdx.x * 2 + 1] = lq[0] + lq[1] + lq[2] + lq[3];
  }
}

__global__ __launch_bounds__(256) void reduce2_kernel(
    const double* __restrict__ part, float* __restrict__ stats) {
  int t = threadIdx.x;
  double s = part[t * 2], q = part[t * 2 + 1];
  #pragma unroll
  for (int o = 32; o >= 1; o >>= 1) { s += __shfl_xor(s, o); q += __shfl_xor(q, o); }
  __shared__ double ls[4], lq[4];
  int lane = t & 63, wid = t >> 6;
  if (lane == 0) { ls[wid] = s; lq[wid] = q; }
  __syncthreads();
  if (t == 0) {
    double S = ls[0] + ls[1] + ls[2] + ls[3];
    double Q = lq[0] + lq[1] + lq[2] + lq[3];
    double n = 262144.0;
    double mean = S / n;
    double var  = (Q - n * mean * mean) / (n - 1.0);
    stats[0] = (float)mean;
    stats[1] = (float)(1.0 / sqrt(var));
  }
}

__global__ __launch_bounds__(256) void norm4_kernel(
    const float4* __restrict__ enc, const float* __restrict__ stats,
    float4* __restrict__ out) {
  int i = blockIdx.x * 256 + threadIdx.x;  // over 65536
  float mean = stats[0], inv = stats[1];
  float4 v = enc[i];
  v.x = (v.x - mean) * inv + 1e-10f;
  v.y = (v.y - mean) * inv + 1e-10f;
  v.z = (v.z - mean) * inv + 1e-10f;
  v.w = (v.w - mean) * inv + 1e-10f;
  out[i] = v;
}

// ---------------------------------------------------------------------------
extern "C" void kernel_launch(void* const* d_in, const int* in_sizes, int n_in,
                              void* d_out, int out_size, void* d_ws, size_t ws_size,
                              hipStream_t stream) {
  const float* state   = (const float*)d_in[0];
  const float* conv_w1 = (const float*)d_in[1];
  const float* conv_b1 = (const float*)d_in[2];
  const float* conv_w2 = (const float*)d_in[3];
  const float* conv_b2 = (const float*)d_in[4];
  const float* conv_w3 = (const float*)d_in[5];
  const float* conv_b3 = (const float*)d_in[6];
  const float* pre_w   = (const float*)d_in[7];
  const float* pre_b   = (const float*)d_in[8];
  const float* pos_w   = (const float*)d_in[9];
  const float* ln1_g   = (const float*)d_in[10];
  const float* ln1_b   = (const float*)d_in[11];
  const float* enc_w   = (const float*)d_in[12];
  const float* enc_bi  = (const float*)d_in[13];
  const float* ln2_g   = (const float*)d_in[14];
  const float* ln2_b   = (const float*)d_in[15];
  const float* ffn_w1  = (const float*)d_in[16];
  const float* ffn_b1  = (const float*)d_in[17];
  const float* ffn_w2  = (const float*)d_in[18];
  const float* ffn_b2  = (const float*)d_in[19];
  const float* emb_w   = (const float*)d_in[20];
  const float* emb_b   = (const float*)d_in[21];
  float* out = (float*)d_out;
  char* ws = (char*)d_ws;

  // conv chunking: use full-size intermediates if ws allows (~258 MB needed)
  int nch = (ws_size >= (270ull << 20)) ? 1 : 4;
  int ipc = 1024 / nch;                       // images per chunk
  size_t S1 = (size_t)ipc * 46080 * 4;        // c1c bytes (16*48*60 per image)
  size_t S2 = (size_t)ipc * 11520 * 4;        // c2c bytes (16*24*30 per image)

  float*  c1c  = (float*)ws;
  float*  c2c  = (float*)(ws + S1);
  float*  c3   = (float*)(ws + S1 + S2);      // 1024*2880*4 = 11796480
  char*   rest = ws + S1 + S2 + 11796480;
  float*  x    = (float*)rest;                // 1 MB
  float*  xn   = (float*)(rest + 1048576);    // 1 MB
  float*  qkv  = (float*)(rest + 2097152);    // 3 MB
  float*  h1   = (float*)(rest + 5242880);    // 4 MB
  float*  encb = (float*)(rest + 9437184);    // 1 MB
  double* part = (double*)(rest + 10485760);  // 4 KB
  float*  stats= (float*)(rest + 10485760 + 4096);

  for (int ch = 0; ch < nch; ch++) {
    size_t so = (size_t)ch * ipc;
    conv1_kernel<<<ipc * 2880 / 256, 256, 0, stream>>>(
        state + so * 34560, conv_w1, conv_b1, c1c);
    conv16_kernel<48, 60, 24, 30><<<ipc * 720 / 256, 256, 0, stream>>>(
        c1c, conv_w2, conv_b2, c2c);
    conv16_kernel<24, 30, 12, 15><<<ipc * 180 / 256, 256, 0, stream>>>(
        c2c, conv_w3, conv_b3, c3 + so * 2880);
  }

  // pre projection: x = pre_b + pos, then split-K atomic (12 x 240)
  initpre4_kernel<<<256, 256, 0, stream>>>(
      (float4*)x, (const float4*)pre_b, (const float4*)pos_w);
  gemm3_kernel<<<dim3(2, 8, 12), 256, 0, stream>>>(
      c3, pre_w, x, 1024, 256, 2880, 240);

  for (int k = 0; k < 4; k++) {
    ln_kernel<<<256, 256, 0, stream>>>(x, ln1_g + k * 256, ln1_b + k * 256, xn);
    initbias4_kernel<<<768, 256, 0, stream>>>(
        (float4*)qkv, (const float4*)(enc_bi + k * 768), 192);
    gemm3_kernel<<<dim3(6, 8, 4), 256, 0, stream>>>(
        xn, enc_w + (size_t)k * 256 * 768, qkv, 1024, 768, 256, 64);
    attn_fused_kernel<<<512, 256, 0, stream>>>(qkv, x);
    ln_kernel<<<256, 256, 0, stream>>>(x, ln2_g + k * 256, ln2_b + k * 256, x);
    hipMemsetAsync(h1, 0, 4194304, stream);
    gemm3_kernel<<<dim3(8, 8, 4), 256, 0, stream>>>(
        x, ffn_w1 + (size_t)k * 256 * 1024, h1, 1024, 1024, 256, 64);
    gelubias4_kernel<<<1024, 256, 0, stream>>>(
        (float4*)h1, (const float4*)(ffn_b1 + k * 1024));
    addbias4_kernel<<<256, 256, 0, stream>>>(
        (float4*)x, (const float4*)(ffn_b2 + k * 256));
    gemm3_kernel<<<dim3(2, 8, 16), 256, 0, stream>>>(
        h1, ffn_w2 + (size_t)k * 1024 * 256, x, 1024, 256, 1024, 64);
  }

  // final projection: encb = emb_b, split-K atomic (8 x 32)
  initbias4_kernel<<<256, 256, 0, stream>>>(
      (float4*)encb, (const float4*)emb_b, 64);
  gemm3_kernel<<<dim3(2, 8, 8), 256, 0, stream>>>(
      x, emb_w, encb, 1024, 256, 256, 32);

  reduce1_kernel<<<256, 256, 0, stream>>>(encb, part);
  reduce2_kernel<<<1, 256, 0, stream>>>(part, stats);
  norm4_kernel<<<256, 256, 0, stream>>>((const float4*)encb, stats, (float4*)out);
}

// Round 8
// 1003.152 us; speedup vs baseline: 2.0104x; 2.0104x over previous
//
#include <hip/hip_runtime.h>
#include <hip/hip_bf16.h>
#include <math.h>

// ---------------------------------------------------------------------------
// AttentionEncoderModel on MI355X — round 5 (resubmit x3): bf16x3 (split-bf16)
// MFMA GEMM tower with fp32 accumulate. Convs + attention unchanged.
// ---------------------------------------------------------------------------

#define DMODEL 256
#define SEQ    512

typedef __attribute__((ext_vector_type(8))) short bf16x8;
typedef __attribute__((ext_vector_type(4))) float f32x4;

static __device__ __forceinline__ unsigned short f2bf(float v) {
  __hip_bfloat16 h = __float2bfloat16(v);
  return *reinterpret_cast<unsigned short*>(&h);
}
static __device__ __forceinline__ float bf2f(unsigned short u) {
  __hip_bfloat16 h;
  *reinterpret_cast<unsigned short*>(&h) = u;
  return __bfloat162float(h);
}
static __device__ __forceinline__ void split2(float v, unsigned short& h,
                                              unsigned short& l) {
  h = f2bf(v);
  l = f2bf(v - bf2f(h));
}

// ---------------- conv1: 3->16, in 96x120 -> out 48x60 ----------------------
__global__ __launch_bounds__(256) void conv1_kernel(
    const float* __restrict__ in, const float* __restrict__ w,
    const float* __restrict__ bias, float* __restrict__ out) {
  __shared__ float wsm[768];
  int t = threadIdx.x;
  for (int i = t; i < 768; i += 256) wsm[i] = w[i];
  __syncthreads();
  int idx = blockIdx.x * 256 + t;
  int ox = idx % 60;
  int oy = (idx / 60) % 48;
  int n  = idx / (60 * 48);
  int iy0 = oy * 2 - 1, ix0 = ox * 2 - 1;
  float win[3][16];
  #pragma unroll
  for (int ic = 0; ic < 3; ic++) {
    #pragma unroll
    for (int ky = 0; ky < 4; ky++) {
      int iy = iy0 + ky;
      #pragma unroll
      for (int kx = 0; kx < 4; kx++) {
        int ix = ix0 + kx;
        bool ok = (iy >= 0) && (iy < 96) && (ix >= 0) && (ix < 120);
        win[ic][ky * 4 + kx] = ok ? in[((n * 3 + ic) * 96 + iy) * 120 + ix] : 0.f;
      }
    }
  }
  #pragma unroll
  for (int oc = 0; oc < 16; oc++) {
    float acc = bias[oc];
    const float* wp = &wsm[oc * 48];
    #pragma unroll
    for (int ic = 0; ic < 3; ic++)
      #pragma unroll
      for (int k = 0; k < 16; k++)
        acc = fmaf(win[ic][k], wp[ic * 16 + k], acc);
    out[((n * 16 + oc) * 48 + oy) * 60 + ox] = fmaxf(acc, 0.f);
  }
}

// ---------------- conv 16->16 (conv2 and conv3) -----------------------------
template <int IH, int IW, int OH, int OW>
__global__ __launch_bounds__(256) void conv16_kernel(
    const float* __restrict__ in, const float* __restrict__ w,
    const float* __restrict__ bias, float* __restrict__ out) {
  __shared__ float wsm[4096];
  int t = threadIdx.x;
  for (int i = t; i < 4096; i += 256) wsm[i] = w[i];
  __syncthreads();
  int idx = blockIdx.x * 256 + t;
  int ox = idx % OW;
  int oy = (idx / OW) % OH;
  int n  = idx / (OW * OH);
  int iy0 = oy * 2 - 1, ix0 = ox * 2 - 1;
  float acc[16];
  #pragma unroll
  for (int oc = 0; oc < 16; oc++) acc[oc] = bias[oc];
  for (int ic = 0; ic < 16; ic++) {
    float win[16];
    #pragma unroll
    for (int ky = 0; ky < 4; ky++) {
      int iy = iy0 + ky;
      #pragma unroll
      for (int kx = 0; kx < 4; kx++) {
        int ix = ix0 + kx;
        bool ok = (iy >= 0) && (iy < IH) && (ix >= 0) && (ix < IW);
        win[ky * 4 + kx] = ok ? in[((n * 16 + ic) * IH + iy) * IW + ix] : 0.f;
      }
    }
    #pragma unroll
    for (int oc = 0; oc < 16; oc++) {
      const float* wp = &wsm[(oc * 16 + ic) * 16];
      float a = acc[oc];
      #pragma unroll
      for (int k = 0; k < 16; k++) a = fmaf(win[k], wp[k], a);
      acc[oc] = a;
    }
  }
  #pragma unroll
  for (int oc = 0; oc < 16; oc++)
    out[((n * 16 + oc) * OH + oy) * OW + ox] = fmaxf(acc[oc], 0.f);
}

// ---------------- weight transpose + bf16 split -----------------------------
// W [K][N] fp32 (batch z) -> Th/Tl [N][K] bf16 hi/lo planes.
__global__ __launch_bounds__(256) void tcvt_kernel(
    const float* __restrict__ W, unsigned short* __restrict__ Th,
    unsigned short* __restrict__ Tl, int K, int N) {
  __shared__ float lds[32][33];
  int t = threadIdx.x;
  int kt = blockIdx.x, nt = blockIdx.y, b = blockIdx.z;
  const float* Wb = W + (size_t)b * K * N;
  unsigned short* Thb = Th + (size_t)b * K * N;
  unsigned short* Tlb = Tl + (size_t)b * K * N;
  int c = t & 31, r0 = (t >> 5) * 4;
  #pragma unroll
  for (int i = 0; i < 4; i++)
    lds[r0 + i][c] = Wb[(size_t)(kt * 32 + r0 + i) * N + nt * 32 + c];
  __syncthreads();
  #pragma unroll
  for (int i = 0; i < 4; i++) {
    float v = lds[c][r0 + i];
    unsigned short h, l;
    split2(v, h, l);
    size_t o = (size_t)(nt * 32 + r0 + i) * K + kt * 32 + c;
    Thb[o] = h;
    Tlb[o] = l;
  }
}

// ---------------- fp32 -> bf16 hi/lo pair conversion ------------------------
__global__ __launch_bounds__(256) void cvtpair_kernel(
    const float4* __restrict__ in, unsigned short* __restrict__ oh,
    unsigned short* __restrict__ ol) {
  int i = blockIdx.x * 256 + threadIdx.x;
  float4 v = in[i];
  ushort4 H, L;
  split2(v.x, H.x, L.x);
  split2(v.y, H.y, L.y);
  split2(v.z, H.z, L.z);
  split2(v.w, H.w, L.w);
  *(ushort4*)&oh[i * 4] = H;
  *(ushort4*)&ol[i * 4] = L;
}

// ---------------- bf16x3 MFMA GEMM ------------------------------------------
// C[M,N] = A @ B with A=[M,K] (hi/lo bf16, row-major), B passed as
// Bt=[N,K] (hi/lo bf16, row-major). 128x128 tile, 4 waves (2x2), each wave
// 64x64 via 4x4 fragments of mfma_f32_16x16x32_bf16. Three products
// (hh, hl, lh) give ~fp32 accuracy.
// EPI: 0 = C=acc+bias, 1 = Ch/Cl = split(gelu(acc+bias)), 2 = atomicAdd to C.
template <int EPI>
__global__ __launch_bounds__(256) void gemm_mfma_kernel(
    const unsigned short* __restrict__ Ah, const unsigned short* __restrict__ Al,
    const unsigned short* __restrict__ Bh, const unsigned short* __restrict__ Bl,
    const float* __restrict__ bias, float* __restrict__ C,
    unsigned short* __restrict__ Ch, unsigned short* __restrict__ Cl,
    int M, int N, int K, int klen) {
  __shared__ unsigned short As[2][128 * 40];   // [hi/lo][row*40 + k], pad 40
  __shared__ unsigned short Bs[2][128 * 40];
  int t = threadIdx.x;
  int n0 = blockIdx.x * 128, m0 = blockIdx.y * 128;
  int kb = blockIdx.z * klen;
  int w = t >> 6, l = t & 63;
  int wr = w >> 1, wc = w & 1;
  int fr = l & 15, fq = l >> 4;
  f32x4 acc[4][4];
  #pragma unroll
  for (int i = 0; i < 4; i++)
    #pragma unroll
    for (int j = 0; j < 4; j++) acc[i][j] = (f32x4){0.f, 0.f, 0.f, 0.f};

  for (int kt = 0; kt < klen; kt += 32) {
    int kg = kb + kt;
    #pragma unroll
    for (int s = 0; s < 2; s++) {
      int q = t + 256 * s;
      int row = q >> 2, ko = (q & 3) << 3;
      *(int4*)&As[0][row * 40 + ko] =
          *(const int4*)&Ah[(size_t)(m0 + row) * K + kg + ko];
      *(int4*)&As[1][row * 40 + ko] =
          *(const int4*)&Al[(size_t)(m0 + row) * K + kg + ko];
      *(int4*)&Bs[0][row * 40 + ko] =
          *(const int4*)&Bh[(size_t)(n0 + row) * K + kg + ko];
      *(int4*)&Bs[1][row * 40 + ko] =
          *(const int4*)&Bl[(size_t)(n0 + row) * K + kg + ko];
    }
    __syncthreads();
    bf16x8 ah[4], al4[4], bh4[4], bl4[4];
    #pragma unroll
    for (int fm = 0; fm < 4; fm++) {
      int ro = (wr * 64 + fm * 16 + fr) * 40 + fq * 8;
      ah[fm]  = *(const bf16x8*)&As[0][ro];
      al4[fm] = *(const bf16x8*)&As[1][ro];
    }
    #pragma unroll
    for (int fn = 0; fn < 4; fn++) {
      int ro = (wc * 64 + fn * 16 + fr) * 40 + fq * 8;
      bh4[fn] = *(const bf16x8*)&Bs[0][ro];
      bl4[fn] = *(const bf16x8*)&Bs[1][ro];
    }
    #pragma unroll
    for (int fm = 0; fm < 4; fm++)
      #pragma unroll
      for (int fn = 0; fn < 4; fn++) {
        acc[fm][fn] = __builtin_amdgcn_mfma_f32_16x16x32_bf16(
            ah[fm], bh4[fn], acc[fm][fn], 0, 0, 0);
        acc[fm][fn] = __builtin_amdgcn_mfma_f32_16x16x32_bf16(
            ah[fm], bl4[fn], acc[fm][fn], 0, 0, 0);
        acc[fm][fn] = __builtin_amdgcn_mfma_f32_16x16x32_bf16(
            al4[fm], bh4[fn], acc[fm][fn], 0, 0, 0);
      }
    __syncthreads();
  }

  #pragma unroll
  for (int fm = 0; fm < 4; fm++) {
    int rbase = m0 + wr * 64 + fm * 16 + fq * 4;
    #pragma unroll
    for (int fn = 0; fn < 4; fn++) {
      int col = n0 + wc * 64 + fn * 16 + fr;
      #pragma unroll
      for (int i = 0; i < 4; i++) {
        int m = rbase + i;
        float v = acc[fm][fn][i];
        if (EPI == 2) {
          atomicAdd(&C[(size_t)m * N + col], v);
        } else if (EPI == 0) {
          C[(size_t)m * N + col] = v + bias[col];
        } else {
          float g = v + bias[col];
          g = 0.5f * g * (1.f + erff(g * 0.70710678118654752f));
          unsigned short hh, ll;
          split2(g, hh, ll);
          Ch[(size_t)m * N + col] = hh;
          Cl[(size_t)m * N + col] = ll;
        }
      }
    }
  }
}

// ---------------- glue -------------------------------------------------------
__global__ __launch_bounds__(256) void initpre4_kernel(
    float4* __restrict__ C, const float4* __restrict__ bias,
    const float4* __restrict__ pos) {
  int i = blockIdx.x * 256 + threadIdx.x;
  int n4 = i & 63;
  int m = i >> 6;
  float4 b = bias[n4], p = pos[(m & (SEQ - 1)) * 64 + n4];
  C[i] = make_float4(b.x + p.x, b.y + p.y, b.z + p.z, b.w + p.w);
}

__global__ __launch_bounds__(256) void addbias4_kernel(
    float4* __restrict__ C, const float4* __restrict__ bias) {
  int i = blockIdx.x * 256 + threadIdx.x;
  float4 v = C[i], b = bias[i & 63];
  v.x += b.x; v.y += b.y; v.z += b.z; v.w += b.w;
  C[i] = v;
}

// ---------------- LayerNorm variants ----------------------------------------
// ln1: read x, write bf16 hi/lo pair only (feeds GEMM A side).
__global__ __launch_bounds__(256) void ln1_bf_kernel(
    const float* __restrict__ x, const float* __restrict__ g,
    const float* __restrict__ b, unsigned short* __restrict__ oh,
    unsigned short* __restrict__ ol) {
  int lane = threadIdx.x & 63;
  int wid  = threadIdx.x >> 6;
  int row  = blockIdx.x * 4 + wid;
  const float* xr = x + row * DMODEL;
  float v[4];
  #pragma unroll
  for (int i = 0; i < 4; i++) v[i] = xr[lane + 64 * i];
  float s = v[0] + v[1] + v[2] + v[3];
  #pragma unroll
  for (int o = 32; o >= 1; o >>= 1) s += __shfl_xor(s, o);
  float mu = s * (1.f / 256.f);
  float sq = 0.f;
  #pragma unroll
  for (int i = 0; i < 4; i++) { float d = v[i] - mu; sq = fmaf(d, d, sq); }
  #pragma unroll
  for (int o = 32; o >= 1; o >>= 1) sq += __shfl_xor(sq, o);
  float rs = rsqrtf(sq * (1.f / 256.f) + 1e-5f);
  #pragma unroll
  for (int i = 0; i < 4; i++) {
    int c = lane + 64 * i;
    float vv = (v[i] - mu) * rs * g[c] + b[c];
    unsigned short h, l;
    split2(vv, h, l);
    oh[row * DMODEL + c] = h;
    ol[row * DMODEL + c] = l;
  }
}

// ln2: in-place fp32 x (residual stream) + bf16 pair (feeds ffn1 A).
__global__ __launch_bounds__(256) void ln2_bf_kernel(
    float* __restrict__ x, const float* __restrict__ g,
    const float* __restrict__ b, unsigned short* __restrict__ oh,
    unsigned short* __restrict__ ol) {
  int lane = threadIdx.x & 63;
  int wid  = threadIdx.x >> 6;
  int row  = blockIdx.x * 4 + wid;
  float* xr = x + row * DMODEL;
  float v[4];
  #pragma unroll
  for (int i = 0; i < 4; i++) v[i] = xr[lane + 64 * i];
  float s = v[0] + v[1] + v[2] + v[3];
  #pragma unroll
  for (int o = 32; o >= 1; o >>= 1) s += __shfl_xor(s, o);
  float mu = s * (1.f / 256.f);
  float sq = 0.f;
  #pragma unroll
  for (int i = 0; i < 4; i++) { float d = v[i] - mu; sq = fmaf(d, d, sq); }
  #pragma unroll
  for (int o = 32; o >= 1; o >>= 1) sq += __shfl_xor(sq, o);
  float rs = rsqrtf(sq * (1.f / 256.f) + 1e-5f);
  #pragma unroll
  for (int i = 0; i < 4; i++) {
    int c = lane + 64 * i;
    float vv = (v[i] - mu) * rs * g[c] + b[c];
    xr[c] = vv;
    unsigned short h, l;
    split2(vv, h, l);
    oh[row * DMODEL + c] = h;
    ol[row * DMODEL + c] = l;
  }
}

// ---------------- fused flash attention (unchanged) -------------------------
__global__ __launch_bounds__(256) void attn_fused_kernel(
    const float* __restrict__ qkv, float* __restrict__ x) {
  __shared__ float Qs[16][36];
  __shared__ float KVs[64][36];
  __shared__ float Osm[16][16][34];

  int t  = threadIdx.x;
  int it = blockIdx.x & 31;
  int h  = (blockIdx.x >> 5) & 7;
  int b  = blockIdx.x >> 8;
  int i0 = it * 16;
  int r  = t >> 4;
  int tx = t & 15;
  int i  = i0 + r;
  int njt = (it >> 2) + 1;

  if (t < 128) {
    int qrow = t >> 3, qd4 = t & 7;
    *(float4*)&Qs[qrow][qd4 * 4] =
        *(const float4*)&qkv[(b * SEQ + i0 + qrow) * 768 + h * 32 + qd4 * 4];
  }
  __syncthreads();
  float4 qv[8];
  #pragma unroll
  for (int d4 = 0; d4 < 8; d4++) qv[d4] = *(float4*)&Qs[r][d4 * 4];

  float s[32];
  #pragma unroll
  for (int z = 0; z < 32; z++) s[z] = -1e30f;

  int kr = t >> 2, kd4 = t & 3;

  #pragma unroll
  for (int jt = 0; jt < 8; jt++) {
    if (jt < njt) {
      int j0 = jt * 64;
      const float* kb = &qkv[(b * SEQ + j0 + kr) * 768 + DMODEL + h * 32];
      *(float4*)&KVs[kr][kd4 * 4]       = *(const float4*)&kb[kd4 * 4];
      *(float4*)&KVs[kr][(kd4 + 4) * 4] = *(const float4*)&kb[(kd4 + 4) * 4];
      __syncthreads();
      #pragma unroll
      for (int q = 0; q < 4; q++) {
        int jl = q * 16 + tx;
        int j  = j0 + jl;
        float acc = 0.f;
        #pragma unroll
        for (int d4 = 0; d4 < 8; d4++) {
          float4 kv = *(float4*)&KVs[jl][d4 * 4];
          acc = fmaf(qv[d4].x, kv.x, acc);
          acc = fmaf(qv[d4].y, kv.y, acc);
          acc = fmaf(qv[d4].z, kv.z, acc);
          acc = fmaf(qv[d4].w, kv.w, acc);
        }
        s[jt * 4 + q] = (j <= i) ? acc * 0.17677669529663687f : -1e30f;
      }
      __syncthreads();
    }
  }

  float mx = -1e30f;
  #pragma unroll
  for (int z = 0; z < 32; z++) mx = fmaxf(mx, s[z]);
  #pragma unroll
  for (int o = 8; o >= 1; o >>= 1) mx = fmaxf(mx, __shfl_xor(mx, o, 16));
  float sum = 0.f;
  #pragma unroll
  for (int z = 0; z < 32; z++) {
    float e = expf(s[z] - mx);
    s[z] = e;
    sum += e;
  }
  #pragma unroll
  for (int o = 8; o >= 1; o >>= 1) sum += __shfl_xor(sum, o, 16);
  float inv = 1.f / sum;
  #pragma unroll
  for (int z = 0; z < 32; z++) s[z] *= inv;

  float o[32];
  #pragma unroll
  for (int z = 0; z < 32; z++) o[z] = 0.f;

  #pragma unroll
  for (int jt = 0; jt < 8; jt++) {
    if (jt < njt) {
      int j0 = jt * 64;
      const float* vb = &qkv[(b * SEQ + j0 + kr) * 768 + 2 * DMODEL + h * 32];
      *(float4*)&KVs[kr][kd4 * 4]       = *(const float4*)&vb[kd4 * 4];
      *(float4*)&KVs[kr][(kd4 + 4) * 4] = *(const float4*)&vb[(kd4 + 4) * 4];
      __syncthreads();
      #pragma unroll
      for (int q = 0; q < 4; q++) {
        int jl = q * 16 + tx;
        float p = s[jt * 4 + q];
        #pragma unroll
        for (int d4 = 0; d4 < 8; d4++) {
          float4 vv = *(float4*)&KVs[jl][d4 * 4];
          o[d4 * 4 + 0] = fmaf(p, vv.x, o[d4 * 4 + 0]);
          o[d4 * 4 + 1] = fmaf(p, vv.y, o[d4 * 4 + 1]);
          o[d4 * 4 + 2] = fmaf(p, vv.z, o[d4 * 4 + 2]);
          o[d4 * 4 + 3] = fmaf(p, vv.w, o[d4 * 4 + 3]);
        }
      }
      __syncthreads();
    }
  }

  #pragma unroll
  for (int d2 = 0; d2 < 16; d2++)
    *(float2*)&Osm[r][tx][d2 * 2] = make_float2(o[d2 * 2], o[d2 * 2 + 1]);
  __syncthreads();
  float2 acc2 = make_float2(0.f, 0.f);
  #pragma unroll
  for (int tx2 = 0; tx2 < 16; tx2++) {
    float2 v = *(float2*)&Osm[r][tx2][tx * 2];
    acc2.x += v.x;
    acc2.y += v.y;
  }
  int base = (b * SEQ + i) * DMODEL + h * 32 + tx * 2;
  float2 old = *(float2*)&x[base];
  old.x += acc2.x;
  old.y += acc2.y;
  *(float2*)&x[base] = old;
}

// ---------------- global standardization ------------------------------------
__global__ __launch_bounds__(256) void reduce1_kernel(
    const float* __restrict__ enc, double* __restrict__ part) {
  int t = threadIdx.x;
  double s = 0.0, q = 0.0;
  for (int i = blockIdx.x * 256 + t; i < 262144; i += 256 * 256) {
    double v = (double)enc[i];
    s += v; q += v * v;
  }
  #pragma unroll
  for (int o = 32; o >= 1; o >>= 1) { s += __shfl_xor(s, o); q += __shfl_xor(q, o); }
  __shared__ double ls[4], lq[4];
  int lane = t & 63, wid = t >> 6;
  if (lane == 0) { ls[wid] = s; lq[wid] = q; }
  __syncthreads();
  if (t == 0) {
    part[blockIdx.x * 2]     = ls[0] + ls[1] + ls[2] + ls[3];
    part[blockIdx.x * 2 + 1] = lq[0] + lq[1] + lq[2] + lq[3];
  }
}

__global__ __launch_bounds__(256) void reduce2_kernel(
    const double* __restrict__ part, float* __restrict__ stats) {
  int t = threadIdx.x;
  double s = part[t * 2], q = part[t * 2 + 1];
  #pragma unroll
  for (int o = 32; o >= 1; o >>= 1) { s += __shfl_xor(s, o); q += __shfl_xor(q, o); }
  __shared__ double ls[4], lq[4];
  int lane = t & 63, wid = t >> 6;
  if (lane == 0) { ls[wid] = s; lq[wid] = q; }
  __syncthreads();
  if (t == 0) {
    double S = ls[0] + ls[1] + ls[2] + ls[3];
    double Q = lq[0] + lq[1] + lq[2] + lq[3];
    double n = 262144.0;
    double mean = S / n;
    double var  = (Q - n * mean * mean) / (n - 1.0);
    stats[0] = (float)mean;
    stats[1] = (float)(1.0 / sqrt(var));
  }
}

__global__ __launch_bounds__(256) void norm4_kernel(
    const float4* __restrict__ enc, const float* __restrict__ stats,
    float4* __restrict__ out) {
  int i = blockIdx.x * 256 + threadIdx.x;
  float mean = stats[0], inv = stats[1];
  float4 v = enc[i];
  v.x = (v.x - mean) * inv + 1e-10f;
  v.y = (v.y - mean) * inv + 1e-10f;
  v.z = (v.z - mean) * inv + 1e-10f;
  v.w = (v.w - mean) * inv + 1e-10f;
  out[i] = v;
}

// ---------------------------------------------------------------------------
extern "C" void kernel_launch(void* const* d_in, const int* in_sizes, int n_in,
                              void* d_out, int out_size, void* d_ws, size_t ws_size,
                              hipStream_t stream) {
  const float* state   = (const float*)d_in[0];
  const float* conv_w1 = (const float*)d_in[1];
  const float* conv_b1 = (const float*)d_in[2];
  const float* conv_w2 = (const float*)d_in[3];
  const float* conv_b2 = (const float*)d_in[4];
  const float* conv_w3 = (const float*)d_in[5];
  const float* conv_b3 = (const float*)d_in[6];
  const float* pre_w   = (const float*)d_in[7];
  const float* pre_b   = (const float*)d_in[8];
  const float* pos_w   = (const float*)d_in[9];
  const float* ln1_g   = (const float*)d_in[10];
  const float* ln1_b   = (const float*)d_in[11];
  const float* enc_w   = (const float*)d_in[12];
  const float* enc_bi  = (const float*)d_in[13];
  const float* ln2_g   = (const float*)d_in[14];
  const float* ln2_b   = (const float*)d_in[15];
  const float* ffn_w1  = (const float*)d_in[16];
  const float* ffn_b1  = (const float*)d_in[17];
  const float* ffn_w2  = (const float*)d_in[18];
  const float* ffn_b2  = (const float*)d_in[19];
  const float* emb_w   = (const float*)d_in[20];
  const float* emb_b   = (const float*)d_in[21];
  float* out = (float*)d_out;

  // workspace layout (cursor-based, 256B aligned)
  int nch = (ws_size >= (310ull << 20)) ? 1 : 4;
  int ipc = 1024 / nch;
  char* p = (char*)d_ws;
  auto alloc = [&](size_t bytes) {
    char* r = p;
    p += (bytes + 255) & ~(size_t)255;
    return r;
  };
  float* c1c = (float*)alloc((size_t)ipc * 46080 * 4);
  float* c2c = (float*)alloc((size_t)ipc * 11520 * 4);
  float* c3  = (float*)alloc(11796480);
  unsigned short* c3h  = (unsigned short*)alloc(5898240);
  unsigned short* c3l  = (unsigned short*)alloc(5898240);
  unsigned short* preTh = (unsigned short*)alloc(1474560);
  unsigned short* preTl = (unsigned short*)alloc(1474560);
  unsigned short* encTh = (unsigned short*)alloc(1572864);
  unsigned short* encTl = (unsigned short*)alloc(1572864);
  unsigned short* f1Th  = (unsigned short*)alloc(2097152);
  unsigned short* f1Tl  = (unsigned short*)alloc(2097152);
  unsigned short* f2Th  = (unsigned short*)alloc(2097152);
  unsigned short* f2Tl  = (unsigned short*)alloc(2097152);
  unsigned short* embTh = (unsigned short*)alloc(131072);
  unsigned short* embTl = (unsigned short*)alloc(131072);
  float* x    = (float*)alloc(1048576);
  unsigned short* xnh = (unsigned short*)alloc(524288);
  unsigned short* xnl = (unsigned short*)alloc(524288);
  unsigned short* xbh = (unsigned short*)alloc(524288);
  unsigned short* xbl = (unsigned short*)alloc(524288);
  float* qkv  = (float*)alloc(3145728);
  unsigned short* h1h = (unsigned short*)alloc(2097152);
  unsigned short* h1l = (unsigned short*)alloc(2097152);
  unsigned short* xfh = (unsigned short*)alloc(524288);
  unsigned short* xfl = (unsigned short*)alloc(524288);
  float* encb = (float*)alloc(1048576);
  double* part = (double*)alloc(4096);
  float* stats = (float*)alloc(256);

  // ---- weight prep (bf16 split + transpose), once per call ----
  tcvt_kernel<<<dim3(90, 8, 1), 256, 0, stream>>>(pre_w, preTh, preTl, 2880, 256);
  tcvt_kernel<<<dim3(8, 24, 4), 256, 0, stream>>>(enc_w, encTh, encTl, 256, 768);
  tcvt_kernel<<<dim3(8, 32, 4), 256, 0, stream>>>(ffn_w1, f1Th, f1Tl, 256, 1024);
  tcvt_kernel<<<dim3(32, 8, 4), 256, 0, stream>>>(ffn_w2, f2Th, f2Tl, 1024, 256);
  tcvt_kernel<<<dim3(8, 8, 1), 256, 0, stream>>>(emb_w, embTh, embTl, 256, 256);

  // ---- convs ----
  for (int ch = 0; ch < nch; ch++) {
    size_t so = (size_t)ch * ipc;
    conv1_kernel<<<ipc * 2880 / 256, 256, 0, stream>>>(
        state + so * 34560, conv_w1, conv_b1, c1c);
    conv16_kernel<48, 60, 24, 30><<<ipc * 720 / 256, 256, 0, stream>>>(
        c1c, conv_w2, conv_b2, c2c);
    conv16_kernel<24, 30, 12, 15><<<ipc * 180 / 256, 256, 0, stream>>>(
        c2c, conv_w3, conv_b3, c3 + so * 2880);
  }
  cvtpair_kernel<<<2880, 256, 0, stream>>>((const float4*)c3, c3h, c3l);

  // ---- pre projection: x = pre_b + pos, += c3 @ pre_w (split-K S=5) ----
  initpre4_kernel<<<256, 256, 0, stream>>>(
      (float4*)x, (const float4*)pre_b, (const float4*)pos_w);
  gemm_mfma_kernel<2><<<dim3(2, 8, 5), 256, 0, stream>>>(
      c3h, c3l, preTh, preTl, nullptr, x, nullptr, nullptr,
      1024, 256, 2880, 576);

  for (int k = 0; k < 4; k++) {
    ln1_bf_kernel<<<256, 256, 0, stream>>>(x, ln1_g + k * 256, ln1_b + k * 256,
                                           xnh, xnl);
    gemm_mfma_kernel<0><<<dim3(6, 8, 1), 256, 0, stream>>>(
        xnh, xnl, encTh + (size_t)k * 196608, encTl + (size_t)k * 196608,
        enc_bi + k * 768, qkv, nullptr, nullptr, 1024, 768, 256, 256);
    attn_fused_kernel<<<512, 256, 0, stream>>>(qkv, x);
    ln2_bf_kernel<<<256, 256, 0, stream>>>(x, ln2_g + k * 256, ln2_b + k * 256,
                                           xbh, xbl);
    gemm_mfma_kernel<1><<<dim3(8, 8, 1), 256, 0, stream>>>(
        xbh, xbl, f1Th + (size_t)k * 262144, f1Tl + (size_t)k * 262144,
        ffn_b1 + k * 1024, nullptr, h1h, h1l, 1024, 1024, 256, 256);
    addbias4_kernel<<<256, 256, 0, stream>>>(
        (float4*)x, (const float4*)(ffn_b2 + k * 256));
    gemm_mfma_kernel<2><<<dim3(2, 8, 4), 256, 0, stream>>>(
        h1h, h1l, f2Th + (size_t)k * 262144, f2Tl + (size_t)k * 262144,
        nullptr, x, nullptr, nullptr, 1024, 256, 1024, 256);
  }

  // ---- final projection ----
  cvtpair_kernel<<<256, 256, 0, stream>>>((const float4*)x, xfh, xfl);
  gemm_mfma_kernel<0><<<dim3(2, 8, 1), 256, 0, stream>>>(
      xfh, xfl, embTh, embTl, emb_b, encb, nullptr, nullptr,
      1024, 256, 256, 256);

  reduce1_kernel<<<256, 256, 0, stream>>>(encb, part);
  reduce2_kernel<<<1, 256, 0, stream>>>(part, stats);
  norm4_kernel<<<256, 256, 0, stream>>>((const float4*)encb, stats, (float4*)out);
}